// Round 5
// baseline (493.344 us; speedup 1.0000x reference)
//
#include <hip/hip_runtime.h>

// Multi-step integrate-and-fire (T=16 scan over independent elements).
// x_seq: (16, 32, 128, 32, 32) fp32 -> spikes same shape.
// R3: per-t load->wait->store chain: latency-bound, HBM 30%, VALU 3%.
// R4: batched-load source got re-fused by the scheduler (VGPR=36 proves <4
//     values live) -> 210us regression. Compiler sank loads to save regs.
// R5: pin with __builtin_amdgcn_sched_barrier(0) around the load batch and
//     the store batch. 16 dwordx4 loads genuinely in flight per wave
//     (16 KB/wave outstanding) -> BW-bound, not latency-bound.

#define T_STEPS 16

typedef float f32x4 __attribute__((ext_vector_type(4)));

__global__ __launch_bounds__(256) void if_scan_kernel(
    const f32x4* __restrict__ x, f32x4* __restrict__ out, int n4) {
    int i = blockIdx.x * blockDim.x + threadIdx.x;
    if (i >= n4) return;

    f32x4 a[T_STEPS];
#pragma unroll
    for (int t = 0; t < T_STEPS; ++t) {
        a[t] = x[(size_t)t * (size_t)n4 + (size_t)i];
    }

    // Nothing crosses: forces all 16 loads issued (and live) before any use.
    __builtin_amdgcn_sched_barrier(0);

    f32x4 v = (f32x4)(0.f);
#pragma unroll
    for (int t = 0; t < T_STEPS; ++t) {
        v += a[t];
        f32x4 s;
        s.x = (v.x >= 1.0f) ? 1.0f : 0.0f;
        s.y = (v.y >= 1.0f) ? 1.0f : 0.0f;
        s.z = (v.z >= 1.0f) ? 1.0f : 0.0f;
        s.w = (v.w >= 1.0f) ? 1.0f : 0.0f;
        v -= s;
        a[t] = s;  // reuse registers for the spike outputs
    }

    __builtin_amdgcn_sched_barrier(0);

#pragma unroll
    for (int t = 0; t < T_STEPS; ++t) {
        __builtin_nontemporal_store(a[t], &out[(size_t)t * (size_t)n4 + (size_t)i]);
    }
}

extern "C" void kernel_launch(void* const* d_in, const int* in_sizes, int n_in,
                              void* d_out, int out_size, void* d_ws, size_t ws_size,
                              hipStream_t stream) {
    const float* x = (const float*)d_in[0];
    float* out = (float*)d_out;

    int total = in_sizes[0];             // 16*32*128*32*32 = 67108864
    int per_step = total / T_STEPS;      // 4194304
    int n4 = per_step / 4;               // 1048576 float4 per timestep

    dim3 block(256);
    dim3 grid((n4 + block.x - 1) / block.x);   // 4096 blocks = 16/CU
    if_scan_kernel<<<grid, block, 0, stream>>>(
        (const f32x4*)x, (f32x4*)out, n4);
}

// Round 6
// 469.670 us; speedup vs baseline: 1.0504x; 1.0504x over previous
//
#include <hip/hip_runtime.h>

// Multi-step integrate-and-fire (T=16 scan over independent elements).
// x_seq: (16, 32, 128, 32, 32) fp32 -> spikes same shape.
// R3-R5: compiler always re-interleaves loads with uses/stores (VGPR stuck
//   at 36, sched_barrier ignored at IR level). Per-iter s_waitcnt vmcnt(0)
//   drains the previous nt-store too (shared vmcnt) -> serialization plateau
//   at ~180-210us, HBM 26%, VALU 3%.
// R6: inline-asm batch: 16 global_load_dwordx4 issued back-to-back from one
//   asm block (saddr + incrementing voffset), single s_waitcnt vmcnt(0) at
//   its end. Outputs are asm results -> uses can't hoist, loads can't sink.
//   Stores (nt, via builtin) depend on compute -> never block loads.

#define T_STEPS 16

typedef float f32x4 __attribute__((ext_vector_type(4)));

__global__ __launch_bounds__(256) void if_scan_kernel(
    const f32x4* __restrict__ x, f32x4* __restrict__ out, int n4) {
    int i = blockIdx.x * blockDim.x + threadIdx.x;
    if (i >= n4) return;

    f32x4 a0, a1, a2, a3, a4, a5, a6, a7;
    f32x4 a8, a9, a10, a11, a12, a13, a14, a15;

    int voff = i * 16;                 // byte offset of this thread's float4
    const int stride = n4 * 16;        // bytes per timestep plane (16 MiB)

    // 16 loads in flight, one wait. saddr form: mem[s[base] + v[off]].
    asm volatile(
        "global_load_dwordx4 %0, %16, %17\n\t"
        "v_add_u32 %16, %18, %16\n\t"
        "global_load_dwordx4 %1, %16, %17\n\t"
        "v_add_u32 %16, %18, %16\n\t"
        "global_load_dwordx4 %2, %16, %17\n\t"
        "v_add_u32 %16, %18, %16\n\t"
        "global_load_dwordx4 %3, %16, %17\n\t"
        "v_add_u32 %16, %18, %16\n\t"
        "global_load_dwordx4 %4, %16, %17\n\t"
        "v_add_u32 %16, %18, %16\n\t"
        "global_load_dwordx4 %5, %16, %17\n\t"
        "v_add_u32 %16, %18, %16\n\t"
        "global_load_dwordx4 %6, %16, %17\n\t"
        "v_add_u32 %16, %18, %16\n\t"
        "global_load_dwordx4 %7, %16, %17\n\t"
        "v_add_u32 %16, %18, %16\n\t"
        "global_load_dwordx4 %8, %16, %17\n\t"
        "v_add_u32 %16, %18, %16\n\t"
        "global_load_dwordx4 %9, %16, %17\n\t"
        "v_add_u32 %16, %18, %16\n\t"
        "global_load_dwordx4 %10, %16, %17\n\t"
        "v_add_u32 %16, %18, %16\n\t"
        "global_load_dwordx4 %11, %16, %17\n\t"
        "v_add_u32 %16, %18, %16\n\t"
        "global_load_dwordx4 %12, %16, %17\n\t"
        "v_add_u32 %16, %18, %16\n\t"
        "global_load_dwordx4 %13, %16, %17\n\t"
        "v_add_u32 %16, %18, %16\n\t"
        "global_load_dwordx4 %14, %16, %17\n\t"
        "v_add_u32 %16, %18, %16\n\t"
        "global_load_dwordx4 %15, %16, %17\n\t"
        "s_waitcnt vmcnt(0)"
        : "=v"(a0), "=v"(a1), "=v"(a2), "=v"(a3),
          "=v"(a4), "=v"(a5), "=v"(a6), "=v"(a7),
          "=v"(a8), "=v"(a9), "=v"(a10), "=v"(a11),
          "=v"(a12), "=v"(a13), "=v"(a14), "=v"(a15),
          "+v"(voff)
        : "s"(x), "s"(stride)
        : "memory");

    f32x4 in[T_STEPS] = {a0, a1, a2, a3, a4, a5, a6, a7,
                         a8, a9, a10, a11, a12, a13, a14, a15};

    f32x4 v = (f32x4)(0.f);
#pragma unroll
    for (int t = 0; t < T_STEPS; ++t) {
        v += in[t];
        f32x4 s;
        s.x = (v.x >= 1.0f) ? 1.0f : 0.0f;
        s.y = (v.y >= 1.0f) ? 1.0f : 0.0f;
        s.z = (v.z >= 1.0f) ? 1.0f : 0.0f;
        s.w = (v.w >= 1.0f) ? 1.0f : 0.0f;
        v -= s;
        __builtin_nontemporal_store(s, &out[(size_t)t * (size_t)n4 + (size_t)i]);
    }
}

extern "C" void kernel_launch(void* const* d_in, const int* in_sizes, int n_in,
                              void* d_out, int out_size, void* d_ws, size_t ws_size,
                              hipStream_t stream) {
    const float* x = (const float*)d_in[0];
    float* out = (float*)d_out;

    int total = in_sizes[0];             // 16*32*128*32*32 = 67108864
    int per_step = total / T_STEPS;      // 4194304
    int n4 = per_step / 4;               // 1048576 float4 per timestep

    dim3 block(256);
    dim3 grid((n4 + block.x - 1) / block.x);   // 4096 blocks = 16/CU
    if_scan_kernel<<<grid, block, 0, stream>>>(
        (const f32x4*)x, (f32x4*)out, n4);
}